// Round 1
// baseline (11634.251 us; speedup 1.0000x reference)
//
#include <hip/hip_runtime.h>
#include <hip/hip_bf16.h>
#include <cstdint>

// Problem shapes (fixed)
#define B      2
#define N      2048
#define DIM    1024
#define HEADS  16
#define DHEAD  64
#define MEMLEN 2048
#define JTOT   (MEMLEN + N)       // 4096
#define INNER  (HEADS * DHEAD)    // 1024
#define SCALE  0.125f             // 64^-0.5

// ---------------------------------------------------------------------------
// Kernel 1: fused projection GEMM.
// A = x [B*N, DIM] row-major. Bcols 0..1023 -> Wq (scaled), 1024..2047 -> Wkv
// k-part, 2048..3071 -> Wkv v-part. Outputs written head-major:
//   qbuf[b][h][i][d], kbuf[b][h][2048+i][d], vbuf[b][h][2048+i][d]
// Tile 64x64, BK=16, 256 threads, 4x4 per thread. fp32 baseline.
// ---------------------------------------------------------------------------
#define BM 64
#define BN 64
#define BK 16

__global__ __launch_bounds__(256) void proj_kernel(
    const float* __restrict__ x, const float* __restrict__ Wq,
    const float* __restrict__ Wkv,
    float* __restrict__ qbuf, float* __restrict__ kbuf, float* __restrict__ vbuf)
{
    const int bn = blockIdx.x;   // 0..47  (col tile)
    const int bm = blockIdx.y;   // 0..63  (row tile)
    const int tid = threadIdx.x;
    const int tx = tid & 15;
    const int ty = tid >> 4;

    __shared__ float As[BK][BM];       // transposed x tile
    __shared__ float Bs[BK][BN];

    // select weight matrix for this column tile
    const int c0 = bn * BN;
    const float* Wsel;
    int wcol0, ldb;
    if (c0 < 1024) { Wsel = Wq;  wcol0 = c0;        ldb = 1024; }
    else           { Wsel = Wkv; wcol0 = c0 - 1024; ldb = 2048; }

    float acc[4][4];
#pragma unroll
    for (int r = 0; r < 4; ++r)
#pragma unroll
        for (int c = 0; c < 4; ++c) acc[r][c] = 0.0f;

    const int lr = tid >> 2;         // 0..63 row for A load
    const int kq = tid & 3;          // float4 index in k
    const int bkk = tid >> 4;        // 0..15 row for B load
    const int cq = tid & 15;         // float4 index in cols

    for (int t = 0; t < DIM / BK; ++t) {
        // load A tile (64 rows x 16 k) transposed into As[k][row]
        float4 av = *(const float4*)&x[(size_t)(bm * BM + lr) * DIM + t * BK + kq * 4];
        As[kq * 4 + 0][lr] = av.x;
        As[kq * 4 + 1][lr] = av.y;
        As[kq * 4 + 2][lr] = av.z;
        As[kq * 4 + 3][lr] = av.w;
        // load B tile (16 k x 64 cols)
        float4 bv = *(const float4*)&Wsel[(size_t)(t * BK + bkk) * ldb + wcol0 + cq * 4];
        *(float4*)&Bs[bkk][cq * 4] = bv;
        __syncthreads();
#pragma unroll
        for (int kk = 0; kk < BK; ++kk) {
            float a0 = As[kk][ty * 4 + 0];
            float a1 = As[kk][ty * 4 + 1];
            float a2 = As[kk][ty * 4 + 2];
            float a3 = As[kk][ty * 4 + 3];
            float b0 = Bs[kk][tx * 4 + 0];
            float b1 = Bs[kk][tx * 4 + 1];
            float b2 = Bs[kk][tx * 4 + 2];
            float b3 = Bs[kk][tx * 4 + 3];
            acc[0][0] += a0 * b0; acc[0][1] += a0 * b1; acc[0][2] += a0 * b2; acc[0][3] += a0 * b3;
            acc[1][0] += a1 * b0; acc[1][1] += a1 * b1; acc[1][2] += a1 * b2; acc[1][3] += a1 * b3;
            acc[2][0] += a2 * b0; acc[2][1] += a2 * b1; acc[2][2] += a2 * b2; acc[2][3] += a2 * b3;
            acc[3][0] += a3 * b0; acc[3][1] += a3 * b1; acc[3][2] += a3 * b2; acc[3][3] += a3 * b3;
        }
        __syncthreads();
    }

    // epilogue: route to qbuf / kbuf / vbuf in head-major layout
#pragma unroll
    for (int r = 0; r < 4; ++r) {
        const int gm = bm * BM + ty * 4 + r;     // global x row
        const int b = gm >> 11;                  // /2048
        const int i = gm & 2047;
#pragma unroll
        for (int cc = 0; cc < 4; ++cc) {
            const int c = c0 + tx * 4 + cc;      // global col 0..3071
            const float v = acc[r][cc];
            if (c < 1024) {
                const int h = c >> 6, d = c & 63;
                qbuf[(((size_t)(b * HEADS + h)) * N + i) * DHEAD + d] = v * SCALE;
            } else if (c < 2048) {
                const int ck = c - 1024;
                const int h = ck >> 6, d = ck & 63;
                kbuf[(((size_t)(b * HEADS + h)) * JTOT + MEMLEN + i) * DHEAD + d] = v;
            } else {
                const int cv = c - 2048;
                const int h = cv >> 6, d = cv & 63;
                vbuf[(((size_t)(b * HEADS + h)) * JTOT + MEMLEN + i) * DHEAD + d] = v;
            }
        }
    }
}

// ---------------------------------------------------------------------------
// Kernel 2: transpose-copy mem_k/mem_v [b, j, h*64+d] -> buf[b][h][j][d], j<2048
// ---------------------------------------------------------------------------
__global__ __launch_bounds__(256) void copy_mem_kernel(
    const float* __restrict__ src, float* __restrict__ dst)
{
    const int total4 = B * MEMLEN * INNER / 4;   // 1048576
    for (int idx = blockIdx.x * blockDim.x + threadIdx.x; idx < total4;
         idx += gridDim.x * blockDim.x) {
        const int flat = idx * 4;
        const int c = flat & 1023;
        const int j = (flat >> 10) & 2047;
        const int b = flat >> 21;
        const int h = c >> 6, d = c & 63;
        float4 val = ((const float4*)src)[idx];
        *(float4*)&dst[(((size_t)(b * HEADS + h)) * JTOT + j) * DHEAD + d] = val;
    }
}

// ---------------------------------------------------------------------------
// Kernel 3: attention. One block (256 threads) per (b, h, i).
// scores in LDS, block softmax, j-parallel PV with 4-way reduction.
// ---------------------------------------------------------------------------
__global__ __launch_bounds__(256) void attn_kernel(
    const float* __restrict__ qbuf, const float* __restrict__ kbuf,
    const float* __restrict__ vbuf, const float* __restrict__ pos_bias,
    float* __restrict__ out)
{
    const int i = blockIdx.x;
    const int h = blockIdx.y;
    const int b = blockIdx.z;
    const int tid = threadIdx.x;

    __shared__ float s_q[DHEAD];
    __shared__ float s_sc[JTOT];
    __shared__ float s_red[256];

    const float* qrow = qbuf + (((size_t)(b * HEADS + h)) * N + i) * DHEAD;
    if (tid < 16) ((float4*)s_q)[tid] = ((const float4*)qrow)[tid];
    __syncthreads();

    const int nj = MEMLEN + i + 1;   // valid keys: j in [0, 2048+i]
    const float* kb = kbuf + ((size_t)(b * HEADS + h)) * JTOT * DHEAD;
    const float* vb = vbuf + ((size_t)(b * HEADS + h)) * JTOT * DHEAD;
    const float* pb = pos_bias + ((size_t)h * N + i) * JTOT;

    // ---- scores + local max ----
    float lmax = -3.4e38f;
    for (int j = tid; j < nj; j += 256) {
        const float4* kr = (const float4*)(kb + (size_t)j * DHEAD);
        float s = 0.0f;
#pragma unroll
        for (int u = 0; u < 16; ++u) {
            float4 kv = kr[u];
            s += s_q[4 * u + 0] * kv.x + s_q[4 * u + 1] * kv.y
               + s_q[4 * u + 2] * kv.z + s_q[4 * u + 3] * kv.w;
        }
        s += pb[j];
        s_sc[j] = s;
        lmax = fmaxf(lmax, s);
    }
    s_red[tid] = lmax;
    __syncthreads();
    for (int off = 128; off > 0; off >>= 1) {
        if (tid < off) s_red[tid] = fmaxf(s_red[tid], s_red[tid + off]);
        __syncthreads();
    }
    const float smax = s_red[0];
    __syncthreads();

    // ---- exp + sum ----
    float lsum = 0.0f;
    for (int j = tid; j < nj; j += 256) {
        float p = __expf(s_sc[j] - smax);
        s_sc[j] = p;
        lsum += p;
    }
    s_red[tid] = lsum;
    __syncthreads();
    for (int off = 128; off > 0; off >>= 1) {
        if (tid < off) s_red[tid] += s_red[tid + off];
        __syncthreads();
    }
    const float rinv = 1.0f / s_red[0];
    __syncthreads();

    // ---- PV: thread owns (d = tid&63, group g = tid>>6) ----
    const int d = tid & 63;
    const int g = tid >> 6;
    float acc = 0.0f;
    for (int j = g; j < nj; j += 4)
        acc += s_sc[j] * vb[(size_t)j * DHEAD + d];
    s_red[tid] = acc;
    __syncthreads();
    if (tid < 64) {
        float o = (s_red[d] + s_red[64 + d] + s_red[128 + d] + s_red[192 + d]) * rinv;
        out[((size_t)(b * N + i)) * INNER + h * DHEAD + d] = o;
    }
}

// ---------------------------------------------------------------------------
extern "C" void kernel_launch(void* const* d_in, const int* in_sizes, int n_in,
                              void* d_out, int out_size, void* d_ws, size_t ws_size,
                              hipStream_t stream)
{
    const float* x        = (const float*)d_in[0];
    const float* mem_k    = (const float*)d_in[1];
    const float* mem_v    = (const float*)d_in[2];
    const float* pos_bias = (const float*)d_in[3];
    const float* Wq       = (const float*)d_in[4];
    const float* Wkv      = (const float*)d_in[5];
    float* out = (float*)d_out;

    // workspace: qbuf 16MB, kbuf 32MB, vbuf 32MB (fp32)
    float* qbuf = (float*)d_ws;                          // B*H*N*64     = 4,194,304
    float* kbuf = qbuf + (size_t)B * HEADS * N * DHEAD;  // B*H*4096*64  = 8,388,608
    float* vbuf = kbuf + (size_t)B * HEADS * JTOT * DHEAD;

    // 1) mem_k/mem_v -> head-major kbuf/vbuf (j < 2048)
    copy_mem_kernel<<<2048, 256, 0, stream>>>(mem_k, kbuf);
    copy_mem_kernel<<<2048, 256, 0, stream>>>(mem_v, vbuf);

    // 2) projections -> qbuf, kbuf/vbuf (j >= 2048)
    dim3 pgrid(3072 / BN, (B * N) / BM);
    proj_kernel<<<pgrid, 256, 0, stream>>>(x, Wq, Wkv, qbuf, kbuf, vbuf);

    // 3) attention
    dim3 agrid(N, HEADS, B);
    attn_kernel<<<agrid, 256, 0, stream>>>(qbuf, kbuf, vbuf, pos_bias, out);
}

// Round 2
// 620.847 us; speedup vs baseline: 18.7393x; 18.7393x over previous
//
#include <hip/hip_runtime.h>
#include <hip/hip_bf16.h>
#include <cstdint>

// Problem shapes (fixed)
#define B_     2
#define N_     2048
#define DIM_   1024
#define H_     16
#define DH_    64
#define MEM_   2048
#define JT_    4096      // MEM_ + N_
#define INNER_ 1024
#define SCALE_ 0.125f

typedef float f32x4 __attribute__((ext_vector_type(4)));
typedef short s16x8 __attribute__((ext_vector_type(8)));
typedef short s16x4 __attribute__((ext_vector_type(4)));

__device__ __forceinline__ short bf16_of(float f) {
    __hip_bfloat16 h = __float2bfloat16(f);   // RNE
    return *(short*)&h;
}

// ---------------------------------------------------------------------------
// Kernel 1: projection GEMM (fp32 compute), bf16 epilogue.
//   q -> qbuf bf16 [b][h][i][64]          (scaled)
//   k -> kbuf bf16 [b][h][2048+i][64]
//   v -> vstage fp32 [b][h][i][64]        (transposed to vtbuf later)
// ---------------------------------------------------------------------------
#define BM 64
#define BN 64
#define BK 16

__global__ __launch_bounds__(256) void proj_kernel(
    const float* __restrict__ x, const float* __restrict__ Wq,
    const float* __restrict__ Wkv,
    short* __restrict__ qbuf, short* __restrict__ kbuf, float* __restrict__ vstage)
{
    const int bn = blockIdx.x;
    const int bm = blockIdx.y;
    const int tid = threadIdx.x;
    const int tx = tid & 15;
    const int ty = tid >> 4;

    __shared__ float As[BK][BM];
    __shared__ float Bs[BK][BN];

    const int c0 = bn * BN;
    const float* Wsel;
    int wcol0, ldb;
    if (c0 < 1024) { Wsel = Wq;  wcol0 = c0;        ldb = 1024; }
    else           { Wsel = Wkv; wcol0 = c0 - 1024; ldb = 2048; }

    float acc[4][4];
#pragma unroll
    for (int r = 0; r < 4; ++r)
#pragma unroll
        for (int c = 0; c < 4; ++c) acc[r][c] = 0.0f;

    const int lr = tid >> 2;
    const int kq = tid & 3;
    const int bkk = tid >> 4;
    const int cq = tid & 15;

    for (int t = 0; t < DIM_ / BK; ++t) {
        float4 av = *(const float4*)&x[(size_t)(bm * BM + lr) * DIM_ + t * BK + kq * 4];
        As[kq * 4 + 0][lr] = av.x;
        As[kq * 4 + 1][lr] = av.y;
        As[kq * 4 + 2][lr] = av.z;
        As[kq * 4 + 3][lr] = av.w;
        float4 bv = *(const float4*)&Wsel[(size_t)(t * BK + bkk) * ldb + wcol0 + cq * 4];
        *(float4*)&Bs[bkk][cq * 4] = bv;
        __syncthreads();
#pragma unroll
        for (int kk = 0; kk < BK; ++kk) {
            float a0 = As[kk][ty * 4 + 0];
            float a1 = As[kk][ty * 4 + 1];
            float a2 = As[kk][ty * 4 + 2];
            float a3 = As[kk][ty * 4 + 3];
            float b0 = Bs[kk][tx * 4 + 0];
            float b1 = Bs[kk][tx * 4 + 1];
            float b2 = Bs[kk][tx * 4 + 2];
            float b3 = Bs[kk][tx * 4 + 3];
            acc[0][0] += a0 * b0; acc[0][1] += a0 * b1; acc[0][2] += a0 * b2; acc[0][3] += a0 * b3;
            acc[1][0] += a1 * b0; acc[1][1] += a1 * b1; acc[1][2] += a1 * b2; acc[1][3] += a1 * b3;
            acc[2][0] += a2 * b0; acc[2][1] += a2 * b1; acc[2][2] += a2 * b2; acc[2][3] += a2 * b3;
            acc[3][0] += a3 * b0; acc[3][1] += a3 * b1; acc[3][2] += a3 * b2; acc[3][3] += a3 * b3;
        }
        __syncthreads();
    }

#pragma unroll
    for (int r = 0; r < 4; ++r) {
        const int gm = bm * BM + ty * 4 + r;
        const int b = gm >> 11;
        const int i = gm & 2047;
#pragma unroll
        for (int cc = 0; cc < 4; ++cc) {
            const int c = c0 + tx * 4 + cc;
            const float v = acc[r][cc];
            if (c < 1024) {
                const int h = c >> 6, d = c & 63;
                qbuf[(((size_t)(b * H_ + h)) * N_ + i) * DH_ + d] = bf16_of(v * SCALE_);
            } else if (c < 2048) {
                const int ck = c - 1024;
                const int h = ck >> 6, d = ck & 63;
                kbuf[(((size_t)(b * H_ + h)) * JT_ + MEM_ + i) * DH_ + d] = bf16_of(v);
            } else {
                const int cv = c - 2048;
                const int h = cv >> 6, d = cv & 63;
                vstage[(((size_t)(b * H_ + h)) * N_ + i) * DH_ + d] = v;
            }
        }
    }
}

// ---------------------------------------------------------------------------
// Kernel 2: mem_k fp32 [b][j][h*64+d] -> kbuf bf16 [b][h][j][d], j<2048
// ---------------------------------------------------------------------------
__global__ __launch_bounds__(256) void copymem_k(
    const float* __restrict__ mem_k, short* __restrict__ kbuf)
{
    const int total4 = B_ * MEM_ * INNER_ / 4;
    for (int idx = blockIdx.x * blockDim.x + threadIdx.x; idx < total4;
         idx += gridDim.x * blockDim.x) {
        const int flat = idx * 4;
        const int c = flat & 1023;
        const int j = (flat >> 10) & 2047;
        const int b = flat >> 21;
        const int h = c >> 6, d = c & 63;
        float4 v = ((const float4*)mem_k)[idx];
        s16x4 o;
        o[0] = bf16_of(v.x); o[1] = bf16_of(v.y);
        o[2] = bf16_of(v.z); o[3] = bf16_of(v.w);
        *(s16x4*)&kbuf[(((size_t)(b * H_ + h)) * JT_ + j) * DH_ + d] = o;
    }
}

// ---------------------------------------------------------------------------
// Kernel 3a: mem_v fp32 [b][j][h*64+d] -> vtbuf bf16 [b][h][d][j], j<2048
// ---------------------------------------------------------------------------
__global__ __launch_bounds__(256) void transpose_memv(
    const float* __restrict__ mem_v, short* __restrict__ vtbuf)
{
    const int jt = blockIdx.x, h = blockIdx.y, b = blockIdx.z;
    const int j0 = jt * 64;
    __shared__ float tile[64][65];
    const int t = threadIdx.x;
    const int r = t >> 2, s4 = (t & 3) * 16;
#pragma unroll
    for (int k = 0; k < 4; ++k) {
        float4 v = *(const float4*)&mem_v[((size_t)(b * MEM_ + j0 + r)) * INNER_ + h * DH_ + s4 + k * 4];
        tile[s4 + k * 4 + 0][r] = v.x;
        tile[s4 + k * 4 + 1][r] = v.y;
        tile[s4 + k * 4 + 2][r] = v.z;
        tile[s4 + k * 4 + 3][r] = v.w;
    }
    __syncthreads();
    short ov[16];
#pragma unroll
    for (int e = 0; e < 16; ++e) ov[e] = bf16_of(tile[r][s4 + e]);
    short* dst = &vtbuf[((size_t)((b * H_ + h) * DH_ + r)) * JT_ + j0 + s4];
    *(s16x8*)&dst[0] = *(s16x8*)&ov[0];
    *(s16x8*)&dst[8] = *(s16x8*)&ov[8];
}

// ---------------------------------------------------------------------------
// Kernel 3b: vstage fp32 [b][h][i][d] -> vtbuf bf16 [b][h][d][2048+i]
// ---------------------------------------------------------------------------
__global__ __launch_bounds__(256) void transpose_vstage(
    const float* __restrict__ vstage, short* __restrict__ vtbuf)
{
    const int it = blockIdx.x, h = blockIdx.y, b = blockIdx.z;
    const int i0 = it * 64;
    __shared__ float tile[64][65];
    const int t = threadIdx.x;
    const int r = t >> 2, s4 = (t & 3) * 16;
    const size_t bh = b * H_ + h;
#pragma unroll
    for (int k = 0; k < 4; ++k) {
        float4 v = *(const float4*)&vstage[(bh * N_ + i0 + r) * DH_ + s4 + k * 4];
        tile[s4 + k * 4 + 0][r] = v.x;
        tile[s4 + k * 4 + 1][r] = v.y;
        tile[s4 + k * 4 + 2][r] = v.z;
        tile[s4 + k * 4 + 3][r] = v.w;
    }
    __syncthreads();
    short ov[16];
#pragma unroll
    for (int e = 0; e < 16; ++e) ov[e] = bf16_of(tile[r][s4 + e]);
    short* dst = &vtbuf[(bh * DH_ + r) * JT_ + MEM_ + i0 + s4];
    *(s16x8*)&dst[0] = *(s16x8*)&ov[0];
    *(s16x8*)&dst[8] = *(s16x8*)&ov[8];
}

// ---------------------------------------------------------------------------
// Kernel 4: flash attention, bf16 MFMA.
// Block = (b, h, 128-query tile). 4 waves x 32 q-rows.
// Per 64-key tile: stage K [64][64]->LDS, V^T [64][64]->LDS;
// S = Q K^T (mfma 16x16x32), + bias (fp32), causal mask, online softmax
// in-register (C-layout: row q=(l>>4)*4+r, col j=l&15), P->LDS bf16,
// O += P V (mfma), fp32 accumulators.
// ---------------------------------------------------------------------------
#define LDK 72
#define LDP 72

__global__ __launch_bounds__(256) void attn_flash(
    const short* __restrict__ qbuf, const short* __restrict__ kbuf,
    const short* __restrict__ vtbuf, const float* __restrict__ pos_bias,
    float* __restrict__ out)
{
    const int b  = blockIdx.x;
    const int h  = blockIdx.y;
    const int zt = blockIdx.z;
    const int i0 = zt * 128;
    const int tid = threadIdx.x;
    const int w = tid >> 6, lane = tid & 63, g = lane >> 4, li = lane & 15;

    __shared__ short K_lds[64 * LDK];
    __shared__ short VT_lds[64 * LDK];
    __shared__ short P_lds[4][32 * LDP];

    const size_t bh = b * H_ + h;
    const short* kg  = kbuf  + bh * (size_t)JT_ * DH_;
    const short* vtg = vtbuf + bh * (size_t)DH_ * JT_;
    const float* pb  = pos_bias + (size_t)h * N_ * JT_;

    // Q fragments (A-frag: row=li, k=(g)*8+e per 32-chunk) — kept in regs
    s16x8 aq[2][2];
#pragma unroll
    for (int mt = 0; mt < 2; ++mt)
#pragma unroll
        for (int kc = 0; kc < 2; ++kc)
            aq[mt][kc] = *(const s16x8*)&qbuf[(bh * N_ + i0 + w * 32 + mt * 16 + li) * DH_ + kc * 32 + g * 8];

    f32x4 o[2][4];
    float m_run[2][4], l_run[2][4];
#pragma unroll
    for (int mt = 0; mt < 2; ++mt) {
#pragma unroll
        for (int dt = 0; dt < 4; ++dt) o[mt][dt] = f32x4{0.f, 0.f, 0.f, 0.f};
#pragma unroll
        for (int r = 0; r < 4; ++r) { m_run[mt][r] = -3.0e38f; l_run[mt][r] = 0.f; }
    }

    const int ntiles = 34 + 2 * zt;    // covers j <= 2048 + i0 + 127
    for (int t = 0; t < ntiles; ++t) {
        const int j0 = t * 64;
        __syncthreads();
        // ---- stage K tile and V^T tile (reg-staged, padded LDS) ----
#pragma unroll
        for (int u = 0; u < 2; ++u) {
            const int c = tid + u * 256;          // 512 chunks of 8 bf16
            const int row = c >> 3, seg = c & 7;
            s16x8 kv = *(const s16x8*)&kg[((size_t)(j0 + row)) * DH_ + seg * 8];
            *(s16x8*)&K_lds[row * LDK + seg * 8] = kv;
            s16x8 vv = *(const s16x8*)&vtg[((size_t)row) * JT_ + j0 + seg * 8];
            *(s16x8*)&VT_lds[row * LDK + seg * 8] = vv;
        }
        __syncthreads();

        // ---- S = Q K^T ----
        f32x4 sacc[2][4];
#pragma unroll
        for (int mt = 0; mt < 2; ++mt)
#pragma unroll
            for (int nt = 0; nt < 4; ++nt) sacc[mt][nt] = f32x4{0.f, 0.f, 0.f, 0.f};
#pragma unroll
        for (int kc = 0; kc < 2; ++kc) {
#pragma unroll
            for (int nt = 0; nt < 4; ++nt) {
                s16x8 bk = *(const s16x8*)&K_lds[(nt * 16 + li) * LDK + kc * 32 + g * 8];
                sacc[0][nt] = __builtin_amdgcn_mfma_f32_16x16x32_bf16(aq[0][kc], bk, sacc[0][nt], 0, 0, 0);
                sacc[1][nt] = __builtin_amdgcn_mfma_f32_16x16x32_bf16(aq[1][kc], bk, sacc[1][nt], 0, 0, 0);
            }
        }

        // ---- bias + mask + online softmax + P writes ----
#pragma unroll
        for (int mt = 0; mt < 2; ++mt) {
            const int qrb = i0 + w * 32 + mt * 16 + g * 4;   // + r = global i
            float s[4][4];
#pragma unroll
            for (int nt = 0; nt < 4; ++nt) {
                const int jg = j0 + nt * 16 + li;
#pragma unroll
                for (int r = 0; r < 4; ++r) {
                    float sv = sacc[mt][nt][r] + pb[(size_t)(qrb + r) * JT_ + jg];
                    s[nt][r] = (jg > MEM_ + qrb + r) ? -1e30f : sv;
                }
            }
            float tm[4], sc[4];
#pragma unroll
            for (int r = 0; r < 4; ++r) {
                tm[r] = fmaxf(fmaxf(s[0][r], s[1][r]), fmaxf(s[2][r], s[3][r]));
                tm[r] = fmaxf(tm[r], __shfl_xor(tm[r], 1));
                tm[r] = fmaxf(tm[r], __shfl_xor(tm[r], 2));
                tm[r] = fmaxf(tm[r], __shfl_xor(tm[r], 4));
                tm[r] = fmaxf(tm[r], __shfl_xor(tm[r], 8));
                const float m_new = fmaxf(m_run[mt][r], tm[r]);
                sc[r] = __expf(m_run[mt][r] - m_new);
                m_run[mt][r] = m_new;
            }
#pragma unroll
            for (int nt = 0; nt < 4; ++nt)
#pragma unroll
                for (int r = 0; r < 4; ++r)
                    s[nt][r] = __expf(s[nt][r] - m_run[mt][r]);
#pragma unroll
            for (int r = 0; r < 4; ++r) {
                float ts = s[0][r] + s[1][r] + s[2][r] + s[3][r];
                ts += __shfl_xor(ts, 1);
                ts += __shfl_xor(ts, 2);
                ts += __shfl_xor(ts, 4);
                ts += __shfl_xor(ts, 8);
                l_run[mt][r] = l_run[mt][r] * sc[r] + ts;
#pragma unroll
                for (int dt = 0; dt < 4; ++dt) o[mt][dt][r] *= sc[r];
            }
#pragma unroll
            for (int nt = 0; nt < 4; ++nt)
#pragma unroll
                for (int r = 0; r < 4; ++r)
                    P_lds[w][(mt * 16 + g * 4 + r) * LDP + nt * 16 + li] = bf16_of(s[nt][r]);
        }
        __syncthreads();

        // ---- O += P V  (A=P from LDS, B=V^T from LDS) ----
#pragma unroll
        for (int kc = 0; kc < 2; ++kc) {
            s16x8 pa0 = *(const s16x8*)&P_lds[w][(0 + li) * LDP + kc * 32 + g * 8];
            s16x8 pa1 = *(const s16x8*)&P_lds[w][(16 + li) * LDP + kc * 32 + g * 8];
#pragma unroll
            for (int dt = 0; dt < 4; ++dt) {
                s16x8 bv = *(const s16x8*)&VT_lds[(dt * 16 + li) * LDK + kc * 32 + g * 8];
                o[0][dt] = __builtin_amdgcn_mfma_f32_16x16x32_bf16(pa0, bv, o[0][dt], 0, 0, 0);
                o[1][dt] = __builtin_amdgcn_mfma_f32_16x16x32_bf16(pa1, bv, o[1][dt], 0, 0, 0);
            }
        }
    }

    // ---- epilogue: out[b][i][h*64+d] = o / l ----
#pragma unroll
    for (int mt = 0; mt < 2; ++mt) {
#pragma unroll
        for (int r = 0; r < 4; ++r) {
            const int i = i0 + w * 32 + mt * 16 + g * 4 + r;
            const float rinv = 1.0f / l_run[mt][r];
#pragma unroll
            for (int dt = 0; dt < 4; ++dt)
                out[((size_t)(b * N_ + i)) * INNER_ + h * DH_ + dt * 16 + li] = o[mt][dt][r] * rinv;
        }
    }
}

// ---------------------------------------------------------------------------
extern "C" void kernel_launch(void* const* d_in, const int* in_sizes, int n_in,
                              void* d_out, int out_size, void* d_ws, size_t ws_size,
                              hipStream_t stream)
{
    const float* x        = (const float*)d_in[0];
    const float* mem_k    = (const float*)d_in[1];
    const float* mem_v    = (const float*)d_in[2];
    const float* pos_bias = (const float*)d_in[3];
    const float* Wq       = (const float*)d_in[4];
    const float* Wkv      = (const float*)d_in[5];
    float* out = (float*)d_out;

    // workspace layout (bytes):
    //   qbuf   bf16  8 MiB   [b][h][i][64]
    //   kbuf   bf16 16 MiB   [b][h][j][64]
    //   vtbuf  bf16 16 MiB   [b][h][64][j]
    //   vstage fp32 16 MiB   [b][h][i][64]
    char* ws = (char*)d_ws;
    short* qbuf   = (short*)(ws);
    short* kbuf   = (short*)(ws + (8u << 20));
    short* vtbuf  = (short*)(ws + (24u << 20));
    float* vstage = (float*)(ws + (40u << 20));

    copymem_k<<<2048, 256, 0, stream>>>(mem_k, kbuf);
    transpose_memv<<<dim3(32, H_, B_), 256, 0, stream>>>(mem_v, vtbuf);

    dim3 pgrid(3072 / BN, (B_ * N_) / BM);
    proj_kernel<<<pgrid, 256, 0, stream>>>(x, Wq, Wkv, qbuf, kbuf, vstage);

    transpose_vstage<<<dim3(32, H_, B_), 256, 0, stream>>>(vstage, vtbuf);

    attn_flash<<<dim3(B_, H_, N_ / 128), 256, 0, stream>>>(qbuf, kbuf, vtbuf, pos_bias, out);
}

// Round 3
// 318.869 us; speedup vs baseline: 36.4860x; 1.9470x over previous
//
#include <hip/hip_runtime.h>
#include <hip/hip_bf16.h>
#include <cstdint>

// Problem shapes (fixed)
#define B_     2
#define N_     2048
#define DIM_   1024
#define H_     16
#define DH_    64
#define MEM_   2048
#define JT_    4096      // MEM_ + N_
#define INNER_ 1024
#define SCALE_ 0.125f

typedef float f32x4 __attribute__((ext_vector_type(4)));
typedef short s16x8 __attribute__((ext_vector_type(8)));
typedef short s16x4 __attribute__((ext_vector_type(4)));

__device__ __forceinline__ short bf16_of(float f) {
    __hip_bfloat16 h = __float2bfloat16(f);   // RNE
    return *(short*)&h;
}

__device__ __forceinline__ void gload16(const void* g, short* l) {
    __builtin_amdgcn_global_load_lds(
        (const __attribute__((address_space(1))) unsigned int*)g,
        (__attribute__((address_space(3))) unsigned int*)l, 16, 0, 0);
}

// ---------------------------------------------------------------------------
// Kernel A: cast x fp32 [4096][1024] -> xb bf16 (row-major)
// ---------------------------------------------------------------------------
__global__ __launch_bounds__(256) void cast_x(
    const float* __restrict__ x, short* __restrict__ xb)
{
    const int total4 = B_ * N_ * DIM_ / 4;   // 1M
    for (int idx = blockIdx.x * blockDim.x + threadIdx.x; idx < total4;
         idx += gridDim.x * blockDim.x) {
        float4 v = ((const float4*)x)[idx];
        s16x4 o;
        o[0] = bf16_of(v.x); o[1] = bf16_of(v.y);
        o[2] = bf16_of(v.z); o[3] = bf16_of(v.w);
        *(s16x4*)&xb[idx * 4] = o;
    }
}

// ---------------------------------------------------------------------------
// Kernel B: transpose-cast weights -> Wt bf16 [3072][1024], Wt[n][k]=W[k][n].
// SCALE folded into q columns (n<1024).
// ---------------------------------------------------------------------------
__global__ __launch_bounds__(256) void cast_w(
    const float* __restrict__ Wq, const float* __restrict__ Wkv,
    short* __restrict__ Wt)
{
    const int kt = blockIdx.x;   // 0..15
    const int nt = blockIdx.y;   // 0..47
    __shared__ float tile[64][65];   // [n_local][k_local]
    const int t = threadIdx.x;
    const int r = t >> 2, s4 = (t & 3) * 16;

    const int n0 = nt * 64;
    const float* src;
    int ldn, nc0;
    if (n0 < 1024) { src = Wq;  ldn = 1024; nc0 = n0; }
    else           { src = Wkv; ldn = 2048; nc0 = n0 - 1024; }
    const float scale = (n0 < 1024) ? SCALE_ : 1.0f;

#pragma unroll
    for (int kq = 0; kq < 4; ++kq) {
        float4 v = *(const float4*)&src[(size_t)(kt * 64 + r) * ldn + nc0 + s4 + kq * 4];
        tile[s4 + kq * 4 + 0][r] = v.x;
        tile[s4 + kq * 4 + 1][r] = v.y;
        tile[s4 + kq * 4 + 2][r] = v.z;
        tile[s4 + kq * 4 + 3][r] = v.w;
    }
    __syncthreads();
    short ov[16];
#pragma unroll
    for (int e = 0; e < 16; ++e) ov[e] = bf16_of(tile[r][s4 + e] * scale);
    short* dst = &Wt[(size_t)(n0 + r) * 1024 + kt * 64 + s4];
    *(s16x8*)&dst[0] = *(s16x8*)&ov[0];
    *(s16x8*)&dst[8] = *(s16x8*)&ov[8];
}

// ---------------------------------------------------------------------------
// Kernel C: MFMA projection GEMM.
//   C[c][i] = sum_k Wt[c][k] * xb[i][k]   (c=0..3071, i=0..4095, K=1024)
// Tile 128(c) x 128(i), BK=64, 4 waves (2x2), 16x16x32 bf16 MFMA.
// A/B staged via global_load_lds (linear LDS dest, XOR-swizzled source slot,
// swizzled ds_read). Epilogue routes through LDS (aliased with A/B):
//   c<1024  -> qbuf bf16 [b][h][i][64]   (scale already folded into Wt)
//   c<2048  -> kbuf bf16 [b][h][2048+i][64]
//   else    -> vtbuf bf16 [b][h][d][2048+i]   (direct transposed write)
// ---------------------------------------------------------------------------
#define PLDC 152   // pad: 304B row stride = 76 dwords = 12 mod 32 -> 2-way banks

__global__ __launch_bounds__(256) void mfma_proj(
    const short* __restrict__ Wt, const short* __restrict__ xb,
    short* __restrict__ qbuf, short* __restrict__ kbuf, short* __restrict__ vtbuf)
{
    const int bc = blockIdx.x;    // 0..23  (c tile)
    const int bi = blockIdx.y;    // 0..31  (i tile)
    const int tid = threadIdx.x;
    const int w = tid >> 6, lane = tid & 63, g = lane >> 4, li = lane & 15;
    const int wr = w >> 1, wc = w & 1;   // wave quadrant: wr->c, wc->i

    __shared__ short smem[128 * PLDC];   // 38 KiB; A/B tiles alias the front
    short* A_lds = smem;                 // [128][64] linear, 8192 shorts
    short* B_lds = smem + 8192;          // [128][64] linear, 8192 shorts

    f32x4 acc[4][4];
#pragma unroll
    for (int m = 0; m < 4; ++m)
#pragma unroll
        for (int n = 0; n < 4; ++n) acc[m][n] = f32x4{0.f, 0.f, 0.f, 0.f};

    const size_t arow0 = (size_t)bc * 128;
    const size_t brow0 = (size_t)bi * 128;

    for (int t = 0; t < 16; ++t) {
        __syncthreads();
        // ---- stage: 1024 chunks of 16B per tile; wave-uniform LDS base ----
#pragma unroll
        for (int u = 0; u < 4; ++u) {
            const int c = (w * 4 + u) * 64 + lane;
            const int row = c >> 3, q = c & 7;
            const int qs = q ^ (row & 7);          // pre-swizzled source slot
            gload16(&Wt[(arow0 + row) * 1024 + t * 64 + qs * 8],
                    &A_lds[(w * 4 + u) * 512 + lane * 8]);
            gload16(&xb[(brow0 + row) * 1024 + t * 64 + qs * 8],
                    &B_lds[(w * 4 + u) * 512 + lane * 8]);
        }
        __syncthreads();
        // ---- 32 MFMA: 4 mt x 4 nt x 2 kc ----
#pragma unroll
        for (int kc = 0; kc < 2; ++kc) {
            s16x8 af[4], bf[4];
#pragma unroll
            for (int mt = 0; mt < 4; ++mt) {
                const int row = wr * 64 + mt * 16 + li;
                af[mt] = *(const s16x8*)&A_lds[row * 64 + ((kc * 4 + g) ^ (row & 7)) * 8];
            }
#pragma unroll
            for (int nt = 0; nt < 4; ++nt) {
                const int row = wc * 64 + nt * 16 + li;
                bf[nt] = *(const s16x8*)&B_lds[row * 64 + ((kc * 4 + g) ^ (row & 7)) * 8];
            }
#pragma unroll
            for (int mt = 0; mt < 4; ++mt)
#pragma unroll
                for (int nt = 0; nt < 4; ++nt)
                    acc[mt][nt] = __builtin_amdgcn_mfma_f32_16x16x32_bf16(af[mt], bf[nt], acc[mt][nt], 0, 0, 0);
        }
    }

    // ---- epilogue ----
    __syncthreads();   // all waves done reading A/B before aliasing smem as C
    const int c0 = bc * 128;
    const int i0g = bi * 128;
    const int b = i0g >> 11;
    const int ii0 = i0g & 2047;

    if (c0 < 2048) {
        // [i][c] layout: lane holds 4 consecutive c at fixed i -> s16x4 stores
#pragma unroll
        for (int mt = 0; mt < 4; ++mt)
#pragma unroll
            for (int nt = 0; nt < 4; ++nt) {
                const int i_l = wc * 64 + nt * 16 + li;
                const int c_l = wr * 64 + mt * 16 + g * 4;
                s16x4 v4;
                v4[0] = bf16_of(acc[mt][nt][0]);
                v4[1] = bf16_of(acc[mt][nt][1]);
                v4[2] = bf16_of(acc[mt][nt][2]);
                v4[3] = bf16_of(acc[mt][nt][3]);
                *(s16x4*)&smem[i_l * PLDC + c_l] = v4;
            }
        __syncthreads();
        const bool isq = (c0 < 1024);
#pragma unroll
        for (int u = 0; u < 8; ++u) {
            const int ch = tid + u * 256;       // 0..2047
            const int i_l = ch >> 4, seg = ch & 15;
            s16x8 v = *(const s16x8*)&smem[i_l * PLDC + seg * 8];
            const int cg = c0 + seg * 8;
            const int h = (cg >> 6) & 15;
            const int d = cg & 63;
            if (isq)
                *(s16x8*)&qbuf[(((size_t)(b * H_ + h)) * N_ + ii0 + i_l) * DH_ + d] = v;
            else
                *(s16x8*)&kbuf[(((size_t)(b * H_ + h)) * JT_ + MEM_ + ii0 + i_l) * DH_ + d] = v;
        }
    } else {
        // [c][i] layout: scalar stores (rows c, col i=li)
#pragma unroll
        for (int mt = 0; mt < 4; ++mt)
#pragma unroll
            for (int nt = 0; nt < 4; ++nt) {
                const int i_l = wc * 64 + nt * 16 + li;
                const int c_b = wr * 64 + mt * 16 + g * 4;
#pragma unroll
                for (int r = 0; r < 4; ++r)
                    smem[(c_b + r) * PLDC + i_l] = bf16_of(acc[mt][nt][r]);
            }
        __syncthreads();
#pragma unroll
        for (int u = 0; u < 8; ++u) {
            const int ch = tid + u * 256;
            const int c_l = ch >> 4, seg = ch & 15;
            s16x8 v = *(const s16x8*)&smem[c_l * PLDC + seg * 8];
            const int cv = c0 + c_l - 2048;
            const int h = cv >> 6, d = cv & 63;
            *(s16x8*)&vtbuf[(((size_t)(b * H_ + h)) * DH_ + d) * JT_ + MEM_ + ii0 + seg * 8] = v;
        }
    }
}

// ---------------------------------------------------------------------------
// Kernel D: mem_k fp32 [b][j][h*64+d] -> kbuf bf16 [b][h][j][d], j<2048
// ---------------------------------------------------------------------------
__global__ __launch_bounds__(256) void copymem_k(
    const float* __restrict__ mem_k, short* __restrict__ kbuf)
{
    const int total4 = B_ * MEM_ * INNER_ / 4;
    for (int idx = blockIdx.x * blockDim.x + threadIdx.x; idx < total4;
         idx += gridDim.x * blockDim.x) {
        const int flat = idx * 4;
        const int c = flat & 1023;
        const int j = (flat >> 10) & 2047;
        const int b = flat >> 21;
        const int h = c >> 6, d = c & 63;
        float4 v = ((const float4*)mem_k)[idx];
        s16x4 o;
        o[0] = bf16_of(v.x); o[1] = bf16_of(v.y);
        o[2] = bf16_of(v.z); o[3] = bf16_of(v.w);
        *(s16x4*)&kbuf[(((size_t)(b * H_ + h)) * JT_ + j) * DH_ + d] = o;
    }
}

// ---------------------------------------------------------------------------
// Kernel E: mem_v fp32 [b][j][h*64+d] -> vtbuf bf16 [b][h][d][j], j<2048
// ---------------------------------------------------------------------------
__global__ __launch_bounds__(256) void transpose_memv(
    const float* __restrict__ mem_v, short* __restrict__ vtbuf)
{
    const int jt = blockIdx.x, h = blockIdx.y, b = blockIdx.z;
    const int j0 = jt * 64;
    __shared__ float tile[64][65];
    const int t = threadIdx.x;
    const int r = t >> 2, s4 = (t & 3) * 16;
#pragma unroll
    for (int k = 0; k < 4; ++k) {
        float4 v = *(const float4*)&mem_v[((size_t)(b * MEM_ + j0 + r)) * INNER_ + h * DH_ + s4 + k * 4];
        tile[s4 + k * 4 + 0][r] = v.x;
        tile[s4 + k * 4 + 1][r] = v.y;
        tile[s4 + k * 4 + 2][r] = v.z;
        tile[s4 + k * 4 + 3][r] = v.w;
    }
    __syncthreads();
    short ov[16];
#pragma unroll
    for (int e = 0; e < 16; ++e) ov[e] = bf16_of(tile[r][s4 + e]);
    short* dst = &vtbuf[((size_t)((b * H_ + h) * DH_ + r)) * JT_ + j0 + s4];
    *(s16x8*)&dst[0] = *(s16x8*)&ov[0];
    *(s16x8*)&dst[8] = *(s16x8*)&ov[8];
}

// ---------------------------------------------------------------------------
// Kernel F: flash attention, bf16 MFMA (unchanged from passing round 2).
// ---------------------------------------------------------------------------
#define LDK 72
#define LDP 72

__global__ __launch_bounds__(256) void attn_flash(
    const short* __restrict__ qbuf, const short* __restrict__ kbuf,
    const short* __restrict__ vtbuf, const float* __restrict__ pos_bias,
    float* __restrict__ out)
{
    const int b  = blockIdx.x;
    const int h  = blockIdx.y;
    const int zt = blockIdx.z;
    const int i0 = zt * 128;
    const int tid = threadIdx.x;
    const int w = tid >> 6, lane = tid & 63, g = lane >> 4, li = lane & 15;

    __shared__ short K_lds[64 * LDK];
    __shared__ short VT_lds[64 * LDK];
    __shared__ short P_lds[4][32 * LDP];

    const size_t bh = b * H_ + h;
    const short* kg  = kbuf  + bh * (size_t)JT_ * DH_;
    const short* vtg = vtbuf + bh * (size_t)DH_ * JT_;
    const float* pb  = pos_bias + (size_t)h * N_ * JT_;

    s16x8 aq[2][2];
#pragma unroll
    for (int mt = 0; mt < 2; ++mt)
#pragma unroll
        for (int kc = 0; kc < 2; ++kc)
            aq[mt][kc] = *(const s16x8*)&qbuf[(bh * N_ + i0 + w * 32 + mt * 16 + li) * DH_ + kc * 32 + g * 8];

    f32x4 o[2][4];
    float m_run[2][4], l_run[2][4];
#pragma unroll
    for (int mt = 0; mt < 2; ++mt) {
#pragma unroll
        for (int dt = 0; dt < 4; ++dt) o[mt][dt] = f32x4{0.f, 0.f, 0.f, 0.f};
#pragma unroll
        for (int r = 0; r < 4; ++r) { m_run[mt][r] = -3.0e38f; l_run[mt][r] = 0.f; }
    }

    const int ntiles = 34 + 2 * zt;
    for (int t = 0; t < ntiles; ++t) {
        const int j0 = t * 64;
        __syncthreads();
#pragma unroll
        for (int u = 0; u < 2; ++u) {
            const int c = tid + u * 256;
            const int row = c >> 3, seg = c & 7;
            s16x8 kv = *(const s16x8*)&kg[((size_t)(j0 + row)) * DH_ + seg * 8];
            *(s16x8*)&K_lds[row * LDK + seg * 8] = kv;
            s16x8 vv = *(const s16x8*)&vtg[((size_t)row) * JT_ + j0 + seg * 8];
            *(s16x8*)&VT_lds[row * LDK + seg * 8] = vv;
        }
        __syncthreads();

        f32x4 sacc[2][4];
#pragma unroll
        for (int mt = 0; mt < 2; ++mt)
#pragma unroll
            for (int nt = 0; nt < 4; ++nt) sacc[mt][nt] = f32x4{0.f, 0.f, 0.f, 0.f};
#pragma unroll
        for (int kc = 0; kc < 2; ++kc) {
#pragma unroll
            for (int nt = 0; nt < 4; ++nt) {
                s16x8 bk = *(const s16x8*)&K_lds[(nt * 16 + li) * LDK + kc * 32 + g * 8];
                sacc[0][nt] = __builtin_amdgcn_mfma_f32_16x16x32_bf16(aq[0][kc], bk, sacc[0][nt], 0, 0, 0);
                sacc[1][nt] = __builtin_amdgcn_mfma_f32_16x16x32_bf16(aq[1][kc], bk, sacc[1][nt], 0, 0, 0);
            }
        }

#pragma unroll
        for (int mt = 0; mt < 2; ++mt) {
            const int qrb = i0 + w * 32 + mt * 16 + g * 4;
            float s[4][4];
#pragma unroll
            for (int nt = 0; nt < 4; ++nt) {
                const int jg = j0 + nt * 16 + li;
#pragma unroll
                for (int r = 0; r < 4; ++r) {
                    float sv = sacc[mt][nt][r] + pb[(size_t)(qrb + r) * JT_ + jg];
                    s[nt][r] = (jg > MEM_ + qrb + r) ? -1e30f : sv;
                }
            }
            float tm[4], sc[4];
#pragma unroll
            for (int r = 0; r < 4; ++r) {
                tm[r] = fmaxf(fmaxf(s[0][r], s[1][r]), fmaxf(s[2][r], s[3][r]));
                tm[r] = fmaxf(tm[r], __shfl_xor(tm[r], 1));
                tm[r] = fmaxf(tm[r], __shfl_xor(tm[r], 2));
                tm[r] = fmaxf(tm[r], __shfl_xor(tm[r], 4));
                tm[r] = fmaxf(tm[r], __shfl_xor(tm[r], 8));
                const float m_new = fmaxf(m_run[mt][r], tm[r]);
                sc[r] = __expf(m_run[mt][r] - m_new);
                m_run[mt][r] = m_new;
            }
#pragma unroll
            for (int nt = 0; nt < 4; ++nt)
#pragma unroll
                for (int r = 0; r < 4; ++r)
                    s[nt][r] = __expf(s[nt][r] - m_run[mt][r]);
#pragma unroll
            for (int r = 0; r < 4; ++r) {
                float ts = s[0][r] + s[1][r] + s[2][r] + s[3][r];
                ts += __shfl_xor(ts, 1);
                ts += __shfl_xor(ts, 2);
                ts += __shfl_xor(ts, 4);
                ts += __shfl_xor(ts, 8);
                l_run[mt][r] = l_run[mt][r] * sc[r] + ts;
#pragma unroll
                for (int dt = 0; dt < 4; ++dt) o[mt][dt][r] *= sc[r];
            }
#pragma unroll
            for (int nt = 0; nt < 4; ++nt)
#pragma unroll
                for (int r = 0; r < 4; ++r)
                    P_lds[w][(mt * 16 + g * 4 + r) * LDP + nt * 16 + li] = bf16_of(s[nt][r]);
        }
        __syncthreads();

#pragma unroll
        for (int kc = 0; kc < 2; ++kc) {
            s16x8 pa0 = *(const s16x8*)&P_lds[w][(0 + li) * LDP + kc * 32 + g * 8];
            s16x8 pa1 = *(const s16x8*)&P_lds[w][(16 + li) * LDP + kc * 32 + g * 8];
#pragma unroll
            for (int dt = 0; dt < 4; ++dt) {
                s16x8 bv = *(const s16x8*)&VT_lds[(dt * 16 + li) * LDK + kc * 32 + g * 8];
                o[0][dt] = __builtin_amdgcn_mfma_f32_16x16x32_bf16(pa0, bv, o[0][dt], 0, 0, 0);
                o[1][dt] = __builtin_amdgcn_mfma_f32_16x16x32_bf16(pa1, bv, o[1][dt], 0, 0, 0);
            }
        }
    }

#pragma unroll
    for (int mt = 0; mt < 2; ++mt) {
#pragma unroll
        for (int r = 0; r < 4; ++r) {
            const int i = i0 + w * 32 + mt * 16 + g * 4 + r;
            const float rinv = 1.0f / l_run[mt][r];
#pragma unroll
            for (int dt = 0; dt < 4; ++dt)
                out[((size_t)(b * N_ + i)) * INNER_ + h * DH_ + dt * 16 + li] = o[mt][dt][r] * rinv;
        }
    }
}

// ---------------------------------------------------------------------------
extern "C" void kernel_launch(void* const* d_in, const int* in_sizes, int n_in,
                              void* d_out, int out_size, void* d_ws, size_t ws_size,
                              hipStream_t stream)
{
    const float* x        = (const float*)d_in[0];
    const float* mem_k    = (const float*)d_in[1];
    const float* mem_v    = (const float*)d_in[2];
    const float* pos_bias = (const float*)d_in[3];
    const float* Wq       = (const float*)d_in[4];
    const float* Wkv      = (const float*)d_in[5];
    float* out = (float*)d_out;

    // workspace layout:
    //   qbuf  bf16  8 MiB   [b][h][i][64]
    //   kbuf  bf16 16 MiB   [b][h][j][64]
    //   vtbuf bf16 16 MiB   [b][h][d][j]
    //   xb    bf16  8 MiB   [4096][1024]
    //   Wt    bf16  6 MiB   [3072][1024]
    char* ws = (char*)d_ws;
    short* qbuf  = (short*)(ws);
    short* kbuf  = (short*)(ws + (8u << 20));
    short* vtbuf = (short*)(ws + (24u << 20));
    short* xb    = (short*)(ws + (40u << 20));
    short* Wt    = (short*)(ws + (48u << 20));

    cast_x<<<2048, 256, 0, stream>>>(x, xb);
    cast_w<<<dim3(16, 48), 256, 0, stream>>>(Wq, Wkv, Wt);
    copymem_k<<<2048, 256, 0, stream>>>(mem_k, kbuf);
    transpose_memv<<<dim3(32, H_, B_), 256, 0, stream>>>(mem_v, vtbuf);

    mfma_proj<<<dim3(24, 32), 256, 0, stream>>>(Wt, xb, qbuf, kbuf, vtbuf);

    attn_flash<<<dim3(B_, H_, N_ / 128), 256, 0, stream>>>(qbuf, kbuf, vtbuf, pos_bias, out);
}

// Round 4
// 314.144 us; speedup vs baseline: 37.0347x; 1.0150x over previous
//
#include <hip/hip_runtime.h>
#include <hip/hip_bf16.h>
#include <cstdint>

// Problem shapes (fixed)
#define B_     2
#define N_     2048
#define DIM_   1024
#define H_     16
#define DH_    64
#define MEM_   2048
#define JT_    4096      // MEM_ + N_
#define INNER_ 1024
#define SCALE_ 0.125f

typedef float f32x4 __attribute__((ext_vector_type(4)));
typedef short s16x8 __attribute__((ext_vector_type(8)));
typedef short s16x4 __attribute__((ext_vector_type(4)));

__device__ __forceinline__ short bf16_of(float f) {
    __hip_bfloat16 h = __float2bfloat16(f);   // RNE
    return *(short*)&h;
}

__device__ __forceinline__ void gload16(const void* g, short* l) {
    __builtin_amdgcn_global_load_lds(
        (const __attribute__((address_space(1))) unsigned int*)g,
        (__attribute__((address_space(3))) unsigned int*)l, 16, 0, 0);
}

// ---------------------------------------------------------------------------
// Kernel A: cast x fp32 [4096][1024] -> xb bf16 (row-major)
// ---------------------------------------------------------------------------
__global__ __launch_bounds__(256) void cast_x(
    const float* __restrict__ x, short* __restrict__ xb)
{
    const int total4 = B_ * N_ * DIM_ / 4;   // 1M
    for (int idx = blockIdx.x * blockDim.x + threadIdx.x; idx < total4;
         idx += gridDim.x * blockDim.x) {
        float4 v = ((const float4*)x)[idx];
        s16x4 o;
        o[0] = bf16_of(v.x); o[1] = bf16_of(v.y);
        o[2] = bf16_of(v.z); o[3] = bf16_of(v.w);
        *(s16x4*)&xb[idx * 4] = o;
    }
}

// ---------------------------------------------------------------------------
// Kernel B: transpose-cast weights -> Wt bf16 [3072][1024], Wt[n][k]=W[k][n].
// SCALE folded into q columns (n<1024).
// ---------------------------------------------------------------------------
__global__ __launch_bounds__(256) void cast_w(
    const float* __restrict__ Wq, const float* __restrict__ Wkv,
    short* __restrict__ Wt)
{
    const int kt = blockIdx.x;   // 0..15
    const int nt = blockIdx.y;   // 0..47
    __shared__ float tile[64][65];   // [n_local][k_local]
    const int t = threadIdx.x;
    const int r = t >> 2, s4 = (t & 3) * 16;

    const int n0 = nt * 64;
    const float* src;
    int ldn, nc0;
    if (n0 < 1024) { src = Wq;  ldn = 1024; nc0 = n0; }
    else           { src = Wkv; ldn = 2048; nc0 = n0 - 1024; }
    const float scale = (n0 < 1024) ? SCALE_ : 1.0f;

#pragma unroll
    for (int kq = 0; kq < 4; ++kq) {
        float4 v = *(const float4*)&src[(size_t)(kt * 64 + r) * ldn + nc0 + s4 + kq * 4];
        tile[s4 + kq * 4 + 0][r] = v.x;
        tile[s4 + kq * 4 + 1][r] = v.y;
        tile[s4 + kq * 4 + 2][r] = v.z;
        tile[s4 + kq * 4 + 3][r] = v.w;
    }
    __syncthreads();
    short ov[16];
#pragma unroll
    for (int e = 0; e < 16; ++e) ov[e] = bf16_of(tile[r][s4 + e] * scale);
    short* dst = &Wt[(size_t)(n0 + r) * 1024 + kt * 64 + s4];
    *(s16x8*)&dst[0] = *(s16x8*)&ov[0];
    *(s16x8*)&dst[8] = *(s16x8*)&ov[8];
}

// ---------------------------------------------------------------------------
// Kernel C: MFMA projection GEMM (unchanged from passing round 3).
//   C[c][i] = sum_k Wt[c][k] * xb[i][k]   (c=0..3071, i=0..4095, K=1024)
// ---------------------------------------------------------------------------
#define PLDC 152

__global__ __launch_bounds__(256) void mfma_proj(
    const short* __restrict__ Wt, const short* __restrict__ xb,
    short* __restrict__ qbuf, short* __restrict__ kbuf, short* __restrict__ vtbuf)
{
    const int bc = blockIdx.x;    // 0..23  (c tile)
    const int bi = blockIdx.y;    // 0..31  (i tile)
    const int tid = threadIdx.x;
    const int w = tid >> 6, lane = tid & 63, g = lane >> 4, li = lane & 15;
    const int wr = w >> 1, wc = w & 1;

    __shared__ short smem[128 * PLDC];
    short* A_lds = smem;
    short* B_lds = smem + 8192;

    f32x4 acc[4][4];
#pragma unroll
    for (int m = 0; m < 4; ++m)
#pragma unroll
        for (int n = 0; n < 4; ++n) acc[m][n] = f32x4{0.f, 0.f, 0.f, 0.f};

    const size_t arow0 = (size_t)bc * 128;
    const size_t brow0 = (size_t)bi * 128;

    for (int t = 0; t < 16; ++t) {
        __syncthreads();
#pragma unroll
        for (int u = 0; u < 4; ++u) {
            const int c = (w * 4 + u) * 64 + lane;
            const int row = c >> 3, q = c & 7;
            const int qs = q ^ (row & 7);
            gload16(&Wt[(arow0 + row) * 1024 + t * 64 + qs * 8],
                    &A_lds[(w * 4 + u) * 512 + lane * 8]);
            gload16(&xb[(brow0 + row) * 1024 + t * 64 + qs * 8],
                    &B_lds[(w * 4 + u) * 512 + lane * 8]);
        }
        __syncthreads();
#pragma unroll
        for (int kc = 0; kc < 2; ++kc) {
            s16x8 af[4], bf[4];
#pragma unroll
            for (int mt = 0; mt < 4; ++mt) {
                const int row = wr * 64 + mt * 16 + li;
                af[mt] = *(const s16x8*)&A_lds[row * 64 + ((kc * 4 + g) ^ (row & 7)) * 8];
            }
#pragma unroll
            for (int nt = 0; nt < 4; ++nt) {
                const int row = wc * 64 + nt * 16 + li;
                bf[nt] = *(const s16x8*)&B_lds[row * 64 + ((kc * 4 + g) ^ (row & 7)) * 8];
            }
#pragma unroll
            for (int mt = 0; mt < 4; ++mt)
#pragma unroll
                for (int nt = 0; nt < 4; ++nt)
                    acc[mt][nt] = __builtin_amdgcn_mfma_f32_16x16x32_bf16(af[mt], bf[nt], acc[mt][nt], 0, 0, 0);
        }
    }

    __syncthreads();
    const int c0 = bc * 128;
    const int i0g = bi * 128;
    const int b = i0g >> 11;
    const int ii0 = i0g & 2047;

    if (c0 < 2048) {
#pragma unroll
        for (int mt = 0; mt < 4; ++mt)
#pragma unroll
            for (int nt = 0; nt < 4; ++nt) {
                const int i_l = wc * 64 + nt * 16 + li;
                const int c_l = wr * 64 + mt * 16 + g * 4;
                s16x4 v4;
                v4[0] = bf16_of(acc[mt][nt][0]);
                v4[1] = bf16_of(acc[mt][nt][1]);
                v4[2] = bf16_of(acc[mt][nt][2]);
                v4[3] = bf16_of(acc[mt][nt][3]);
                *(s16x4*)&smem[i_l * PLDC + c_l] = v4;
            }
        __syncthreads();
        const bool isq = (c0 < 1024);
#pragma unroll
        for (int u = 0; u < 8; ++u) {
            const int ch = tid + u * 256;
            const int i_l = ch >> 4, seg = ch & 15;
            s16x8 v = *(const s16x8*)&smem[i_l * PLDC + seg * 8];
            const int cg = c0 + seg * 8;
            const int h = (cg >> 6) & 15;
            const int d = cg & 63;
            if (isq)
                *(s16x8*)&qbuf[(((size_t)(b * H_ + h)) * N_ + ii0 + i_l) * DH_ + d] = v;
            else
                *(s16x8*)&kbuf[(((size_t)(b * H_ + h)) * JT_ + MEM_ + ii0 + i_l) * DH_ + d] = v;
        }
    } else {
#pragma unroll
        for (int mt = 0; mt < 4; ++mt)
#pragma unroll
            for (int nt = 0; nt < 4; ++nt) {
                const int i_l = wc * 64 + nt * 16 + li;
                const int c_b = wr * 64 + mt * 16 + g * 4;
#pragma unroll
                for (int r = 0; r < 4; ++r)
                    smem[(c_b + r) * PLDC + i_l] = bf16_of(acc[mt][nt][r]);
            }
        __syncthreads();
#pragma unroll
        for (int u = 0; u < 8; ++u) {
            const int ch = tid + u * 256;
            const int c_l = ch >> 4, seg = ch & 15;
            s16x8 v = *(const s16x8*)&smem[c_l * PLDC + seg * 8];
            const int cv = c0 + c_l - 2048;
            const int h = cv >> 6, d = cv & 63;
            *(s16x8*)&vtbuf[(((size_t)(b * H_ + h)) * DH_ + d) * JT_ + MEM_ + ii0 + seg * 8] = v;
        }
    }
}

// ---------------------------------------------------------------------------
// Kernel D: mem_k fp32 [b][j][h*64+d] -> kbuf bf16 [b][h][j][d], j<2048
// ---------------------------------------------------------------------------
__global__ __launch_bounds__(256) void copymem_k(
    const float* __restrict__ mem_k, short* __restrict__ kbuf)
{
    const int total4 = B_ * MEM_ * INNER_ / 4;
    for (int idx = blockIdx.x * blockDim.x + threadIdx.x; idx < total4;
         idx += gridDim.x * blockDim.x) {
        const int flat = idx * 4;
        const int c = flat & 1023;
        const int j = (flat >> 10) & 2047;
        const int b = flat >> 21;
        const int h = c >> 6, d = c & 63;
        float4 v = ((const float4*)mem_k)[idx];
        s16x4 o;
        o[0] = bf16_of(v.x); o[1] = bf16_of(v.y);
        o[2] = bf16_of(v.z); o[3] = bf16_of(v.w);
        *(s16x4*)&kbuf[(((size_t)(b * H_ + h)) * JT_ + j) * DH_ + d] = o;
    }
}

// ---------------------------------------------------------------------------
// Kernel E: mem_v fp32 [b][j][h*64+d] -> vtbuf bf16 [b][h][d][j], j<2048
// ---------------------------------------------------------------------------
__global__ __launch_bounds__(256) void transpose_memv(
    const float* __restrict__ mem_v, short* __restrict__ vtbuf)
{
    const int jt = blockIdx.x, h = blockIdx.y, b = blockIdx.z;
    const int j0 = jt * 64;
    __shared__ float tile[64][65];
    const int t = threadIdx.x;
    const int r = t >> 2, s4 = (t & 3) * 16;
#pragma unroll
    for (int k = 0; k < 4; ++k) {
        float4 v = *(const float4*)&mem_v[((size_t)(b * MEM_ + j0 + r)) * INNER_ + h * DH_ + s4 + k * 4];
        tile[s4 + k * 4 + 0][r] = v.x;
        tile[s4 + k * 4 + 1][r] = v.y;
        tile[s4 + k * 4 + 2][r] = v.z;
        tile[s4 + k * 4 + 3][r] = v.w;
    }
    __syncthreads();
    short ov[16];
#pragma unroll
    for (int e = 0; e < 16; ++e) ov[e] = bf16_of(tile[r][s4 + e]);
    short* dst = &vtbuf[((size_t)((b * H_ + h) * DH_ + r)) * JT_ + j0 + s4];
    *(s16x8*)&dst[0] = *(s16x8*)&ov[0];
    *(s16x8*)&dst[8] = *(s16x8*)&ov[8];
}

// ---------------------------------------------------------------------------
// Kernel F: flash attention, bf16 MFMA.
// 1D grid of 512 blocks, XCD-locality remap:
//   xcd = lid%8 == h%8  -> all 16 q-tiles x 2 batches of a head share an XCD:
//   bias tile read by b=0 twin is an L2 hit for b=1; K/V tiles stream in
//   near-lockstep across the 16 q-tile blocks -> fetched ~once per XCD.
// Kernel body otherwise unchanged from passing round 3.
// ---------------------------------------------------------------------------
#define LDK 72
#define LDP 72

__global__ __launch_bounds__(256) void attn_flash(
    const short* __restrict__ qbuf, const short* __restrict__ kbuf,
    const short* __restrict__ vtbuf, const float* __restrict__ pos_bias,
    float* __restrict__ out)
{
    const int lid = blockIdx.x;                       // 0..511
    const int h   = (lid & 7) | (((lid >> 3) & 1) << 3);
    const int b   = (lid >> 4) & 1;
    const int zt  = lid >> 5;                         // 0..15
    const int i0 = zt * 128;
    const int tid = threadIdx.x;
    const int w = tid >> 6, lane = tid & 63, g = lane >> 4, li = lane & 15;

    __shared__ short K_lds[64 * LDK];
    __shared__ short VT_lds[64 * LDK];
    __shared__ short P_lds[4][32 * LDP];

    const size_t bh = b * H_ + h;
    const short* kg  = kbuf  + bh * (size_t)JT_ * DH_;
    const short* vtg = vtbuf + bh * (size_t)DH_ * JT_;
    const float* pb  = pos_bias + (size_t)h * N_ * JT_;

    s16x8 aq[2][2];
#pragma unroll
    for (int mt = 0; mt < 2; ++mt)
#pragma unroll
        for (int kc = 0; kc < 2; ++kc)
            aq[mt][kc] = *(const s16x8*)&qbuf[(bh * N_ + i0 + w * 32 + mt * 16 + li) * DH_ + kc * 32 + g * 8];

    f32x4 o[2][4];
    float m_run[2][4], l_run[2][4];
#pragma unroll
    for (int mt = 0; mt < 2; ++mt) {
#pragma unroll
        for (int dt = 0; dt < 4; ++dt) o[mt][dt] = f32x4{0.f, 0.f, 0.f, 0.f};
#pragma unroll
        for (int r = 0; r < 4; ++r) { m_run[mt][r] = -3.0e38f; l_run[mt][r] = 0.f; }
    }

    const int ntiles = 34 + 2 * zt;
    for (int t = 0; t < ntiles; ++t) {
        const int j0 = t * 64;
        __syncthreads();
#pragma unroll
        for (int u = 0; u < 2; ++u) {
            const int c = tid + u * 256;
            const int row = c >> 3, seg = c & 7;
            s16x8 kv = *(const s16x8*)&kg[((size_t)(j0 + row)) * DH_ + seg * 8];
            *(s16x8*)&K_lds[row * LDK + seg * 8] = kv;
            s16x8 vv = *(const s16x8*)&vtg[((size_t)row) * JT_ + j0 + seg * 8];
            *(s16x8*)&VT_lds[row * LDK + seg * 8] = vv;
        }
        __syncthreads();

        f32x4 sacc[2][4];
#pragma unroll
        for (int mt = 0; mt < 2; ++mt)
#pragma unroll
            for (int nt = 0; nt < 4; ++nt) sacc[mt][nt] = f32x4{0.f, 0.f, 0.f, 0.f};
#pragma unroll
        for (int kc = 0; kc < 2; ++kc) {
#pragma unroll
            for (int nt = 0; nt < 4; ++nt) {
                s16x8 bk = *(const s16x8*)&K_lds[(nt * 16 + li) * LDK + kc * 32 + g * 8];
                sacc[0][nt] = __builtin_amdgcn_mfma_f32_16x16x32_bf16(aq[0][kc], bk, sacc[0][nt], 0, 0, 0);
                sacc[1][nt] = __builtin_amdgcn_mfma_f32_16x16x32_bf16(aq[1][kc], bk, sacc[1][nt], 0, 0, 0);
            }
        }

#pragma unroll
        for (int mt = 0; mt < 2; ++mt) {
            const int qrb = i0 + w * 32 + mt * 16 + g * 4;
            float s[4][4];
#pragma unroll
            for (int nt = 0; nt < 4; ++nt) {
                const int jg = j0 + nt * 16 + li;
#pragma unroll
                for (int r = 0; r < 4; ++r) {
                    float sv = sacc[mt][nt][r] + pb[(size_t)(qrb + r) * JT_ + jg];
                    s[nt][r] = (jg > MEM_ + qrb + r) ? -1e30f : sv;
                }
            }
            float tm[4], sc[4];
#pragma unroll
            for (int r = 0; r < 4; ++r) {
                tm[r] = fmaxf(fmaxf(s[0][r], s[1][r]), fmaxf(s[2][r], s[3][r]));
                tm[r] = fmaxf(tm[r], __shfl_xor(tm[r], 1));
                tm[r] = fmaxf(tm[r], __shfl_xor(tm[r], 2));
                tm[r] = fmaxf(tm[r], __shfl_xor(tm[r], 4));
                tm[r] = fmaxf(tm[r], __shfl_xor(tm[r], 8));
                const float m_new = fmaxf(m_run[mt][r], tm[r]);
                sc[r] = __expf(m_run[mt][r] - m_new);
                m_run[mt][r] = m_new;
            }
#pragma unroll
            for (int nt = 0; nt < 4; ++nt)
#pragma unroll
                for (int r = 0; r < 4; ++r)
                    s[nt][r] = __expf(s[nt][r] - m_run[mt][r]);
#pragma unroll
            for (int r = 0; r < 4; ++r) {
                float ts = s[0][r] + s[1][r] + s[2][r] + s[3][r];
                ts += __shfl_xor(ts, 1);
                ts += __shfl_xor(ts, 2);
                ts += __shfl_xor(ts, 4);
                ts += __shfl_xor(ts, 8);
                l_run[mt][r] = l_run[mt][r] * sc[r] + ts;
#pragma unroll
                for (int dt = 0; dt < 4; ++dt) o[mt][dt][r] *= sc[r];
            }
#pragma unroll
            for (int nt = 0; nt < 4; ++nt)
#pragma unroll
                for (int r = 0; r < 4; ++r)
                    P_lds[w][(mt * 16 + g * 4 + r) * LDP + nt * 16 + li] = bf16_of(s[nt][r]);
        }
        __syncthreads();

#pragma unroll
        for (int kc = 0; kc < 2; ++kc) {
            s16x8 pa0 = *(const s16x8*)&P_lds[w][(0 + li) * LDP + kc * 32 + g * 8];
            s16x8 pa1 = *(const s16x8*)&P_lds[w][(16 + li) * LDP + kc * 32 + g * 8];
#pragma unroll
            for (int dt = 0; dt < 4; ++dt) {
                s16x8 bv = *(const s16x8*)&VT_lds[(dt * 16 + li) * LDK + kc * 32 + g * 8];
                o[0][dt] = __builtin_amdgcn_mfma_f32_16x16x32_bf16(pa0, bv, o[0][dt], 0, 0, 0);
                o[1][dt] = __builtin_amdgcn_mfma_f32_16x16x32_bf16(pa1, bv, o[1][dt], 0, 0, 0);
            }
        }
    }

#pragma unroll
    for (int mt = 0; mt < 2; ++mt) {
#pragma unroll
        for (int r = 0; r < 4; ++r) {
            const int i = i0 + w * 32 + mt * 16 + g * 4 + r;
            const float rinv = 1.0f / l_run[mt][r];
#pragma unroll
            for (int dt = 0; dt < 4; ++dt)
                out[((size_t)(b * N_ + i)) * INNER_ + h * DH_ + dt * 16 + li] = o[mt][dt][r] * rinv;
        }
    }
}

// ---------------------------------------------------------------------------
extern "C" void kernel_launch(void* const* d_in, const int* in_sizes, int n_in,
                              void* d_out, int out_size, void* d_ws, size_t ws_size,
                              hipStream_t stream)
{
    const float* x        = (const float*)d_in[0];
    const float* mem_k    = (const float*)d_in[1];
    const float* mem_v    = (const float*)d_in[2];
    const float* pos_bias = (const float*)d_in[3];
    const float* Wq       = (const float*)d_in[4];
    const float* Wkv      = (const float*)d_in[5];
    float* out = (float*)d_out;

    // workspace layout:
    //   qbuf  bf16  8 MiB   [b][h][i][64]
    //   kbuf  bf16 16 MiB   [b][h][j][64]
    //   vtbuf bf16 16 MiB   [b][h][d][j]
    //   xb    bf16  8 MiB   [4096][1024]
    //   Wt    bf16  6 MiB   [3072][1024]
    char* ws = (char*)d_ws;
    short* qbuf  = (short*)(ws);
    short* kbuf  = (short*)(ws + (8u << 20));
    short* vtbuf = (short*)(ws + (24u << 20));
    short* xb    = (short*)(ws + (40u << 20));
    short* Wt    = (short*)(ws + (48u << 20));

    cast_x<<<2048, 256, 0, stream>>>(x, xb);
    cast_w<<<dim3(16, 48), 256, 0, stream>>>(Wq, Wkv, Wt);
    copymem_k<<<2048, 256, 0, stream>>>(mem_k, kbuf);
    transpose_memv<<<dim3(32, H_, B_), 256, 0, stream>>>(mem_v, vtbuf);

    mfma_proj<<<dim3(24, 32), 256, 0, stream>>>(Wt, xb, qbuf, kbuf, vtbuf);

    attn_flash<<<512, 256, 0, stream>>>(qbuf, kbuf, vtbuf, pos_bias, out);
}